// Round 2
// baseline (66.987 us; speedup 1.0000x reference)
//
#include <hip/hip_runtime.h>

// Regression_55791625175653
// ref: only c3 used. upsample4(nearest) -> 4^3 ones box conv (SAME, lo=1 hi=2)
//      -> softmax over D(192) -> sum(w * arange(192)) -> out [1,256,512] f32.
//
// Separable coarse-cell form per axis: output phase p touches <=2 coarse
// cells with weights  p=0:(j-1,j)*(1,3)  p=1:(j)*(4)  p=2:(j,j+1)*(3,1)
// p=3:(j,j+1)*(2,2);  OOB cells contribute 0 (zero padding).
//
// Parallelization: 4 lanes per output pixel (D-axis split 4x12 coarse cells),
// shfl_xor(16/32) allreduce for softmax max/sums. 8192 waves -> 32 waves/CU.

#define DC 48
#define HC 64
#define WC 128
#define WOUT 512
#define HOUT 256
#define NPIX (HOUT * WOUT)
#define LOG2E 1.4426950408889634f

__device__ __forceinline__ void axis_weights(int p, int& off, float& w0, float& w1) {
    // p=0: off=-1,(1,3); p=1: off=0,(4,0); p=2: off=0,(3,1); p=3: off=0,(2,2)
    off = (p == 0) ? -1 : 0;
    w0  = (p == 0) ? 1.f : (p == 1) ? 4.f : (p == 2) ? 3.f : 2.f;
    w1  = (p == 0) ? 3.f : (p == 1) ? 0.f : (p == 2) ? 1.f : 2.f;
}

__global__ __launch_bounds__(256)
void regress_kernel(const float* __restrict__ c3, float* __restrict__ out) {
    int lane = threadIdx.x & 63;
    int px   = lane & 15;        // pixel slot within wave
    int q    = lane >> 4;        // D-slice 0..3
    int wv   = threadIdx.x >> 6; // wave in block
    int g    = blockIdx.x * 64 + wv * 16 + px;  // global pixel id

    int w = g & (WOUT - 1);
    int h = g >> 9;

    int jh = h >> 2, ph = h & 3;
    int jw = w >> 2, pw = w & 3;

    int offh, offw;
    float whA, whB, wwA, wwB;
    axis_weights(ph, offh, whA, whB);
    axis_weights(pw, offw, wwA, wwB);

    int jh0 = jh + offh, jh1 = jh0 + 1;
    float wh0 = (jh0 >= 0 && jh0 < HC) ? whA : 0.f;
    float wh1 = (jh1 < HC) ? whB : 0.f;          // jh1 >= 0 always
    jh0 = (jh0 < 0) ? 0 : jh0;
    jh1 = (jh1 > HC - 1) ? HC - 1 : jh1;

    int jw0 = jw + offw, jw1 = jw0 + 1;
    float ww0 = (jw0 >= 0 && jw0 < WC) ? wwA : 0.f;
    float ww1 = (jw1 < WC) ? wwB : 0.f;
    jw0 = (jw0 < 0) ? 0 : jw0;
    jw1 = (jw1 > WC - 1) ? WC - 1 : jw1;

    // fold log2e in here: downstream exp uses raw v_exp_f32 (exp2)
    float w00 = wh0 * ww0 * LOG2E, w01 = wh0 * ww1 * LOG2E;
    float w10 = wh1 * ww0 * LOG2E, w11 = wh1 * ww1 * LOG2E;

    int i00 = jh0 * WC + jw0, i01 = jh0 * WC + jw1;
    int i10 = jh1 * WC + jw0, i11 = jh1 * WC + jw1;

    // this lane's coarse-D slice: jd in [12q, 12q+12), plus halo on each side
    int base = 12 * q;
    float S[14];                       // S[kk] = coarse jd = base-1+kk (log2-scaled)
    #pragma unroll
    for (int kk = 0; kk < 14; ++kk) {
        int jd  = base - 1 + kk;
        bool ok = (jd >= 0) && (jd < DC);
        int jc  = ok ? jd : 0;
        const float* p = c3 + jc * (HC * WC);
        float val = w00 * p[i00] + w01 * p[i01] + w10 * p[i10] + w11 * p[i11];
        S[kk] = ok ? val : 0.f;
    }

    // pass 1: local max over this slice's 48 conv values
    float m = -1e30f;
    #pragma unroll
    for (int i = 0; i < 12; ++i) {
        float Sm = S[i], Sc = S[i + 1], Sp = S[i + 2];
        float x0 = Sm + 3.f * Sc;        // d = 4(base+i)+0
        float x1 = 4.f * Sc;             // +1
        float x2 = 3.f * Sc + Sp;        // +2
        float x3 = 2.f * Sc + 2.f * Sp;  // +3
        m = fmaxf(m, fmaxf(fmaxf(x0, x1), fmaxf(x2, x3)));
    }
    // allreduce max across the 4 D-slices of this pixel (lanes differ in bits 4,5)
    m = fmaxf(m, __shfl_xor(m, 16, 64));
    m = fmaxf(m, __shfl_xor(m, 32, 64));

    // pass 2: softmax accumulation + weighted index (exp2 domain)
    float s = 0.f, sd = 0.f;
    #pragma unroll
    for (int i = 0; i < 12; ++i) {
        float Sm = S[i], Sc = S[i + 1], Sp = S[i + 2];
        float x0 = Sm + 3.f * Sc;
        float x1 = 4.f * Sc;
        float x2 = 3.f * Sc + Sp;
        float x3 = 2.f * Sc + 2.f * Sp;
        float e0 = __builtin_amdgcn_exp2f(x0 - m);
        float e1 = __builtin_amdgcn_exp2f(x1 - m);
        float e2 = __builtin_amdgcn_exp2f(x2 - m);
        float e3 = __builtin_amdgcn_exp2f(x3 - m);
        s += e0 + e1 + e2 + e3;
        float d0 = (float)(4 * (base + i));
        sd = fmaf(e0, d0, sd);
        sd = fmaf(e1, d0 + 1.f, sd);
        sd = fmaf(e2, d0 + 2.f, sd);
        sd = fmaf(e3, d0 + 3.f, sd);
    }
    // allreduce the two sums
    s  += __shfl_xor(s, 16, 64);
    s  += __shfl_xor(s, 32, 64);
    sd += __shfl_xor(sd, 16, 64);
    sd += __shfl_xor(sd, 32, 64);

    if (q == 0) out[g] = sd / s;
}

extern "C" void kernel_launch(void* const* d_in, const int* in_sizes, int n_in,
                              void* d_out, int out_size, void* d_ws, size_t ws_size,
                              hipStream_t stream) {
    (void)in_sizes; (void)n_in; (void)d_ws; (void)ws_size; (void)out_size;
    const float* c3 = (const float*)d_in[2];   // only c3 is used (inference path)
    float* out = (float*)d_out;
    regress_kernel<<<NPIX / 64, 256, 0, stream>>>(c3, out);
}